// Round 12
// baseline (1305.141 us; speedup 1.0000x reference)
//
#include <hip/hip_runtime.h>
#include <math.h>

#define N_NODES 50000
#define N_EDGES 500000

// ---------- f16 pair helpers ----------
typedef _Float16 h2_t __attribute__((ext_vector_type(2)));
__device__ inline float pk(float a, float b) {
    h2_t h; h[0] = (_Float16)a; h[1] = (_Float16)b;
    float r; __builtin_memcpy(&r, &h, 4); return r;
}
__device__ inline float2 upk(float p) {
    h2_t h; __builtin_memcpy(&h, &p, 4);
    return make_float2((float)h[0], (float)h[1]);
}
__device__ inline float dot2f(float pa, float pb, float c) {
    h2_t ha, hb; __builtin_memcpy(&ha, &pa, 4); __builtin_memcpy(&hb, &pb, 4);
    return __builtin_amdgcn_fdot2(ha, hb, c, false);
}

// =================== merged CSR build (CSR1 by dst + CSR2 incidence) ====================
__global__ void k_deg_count_both(const int* __restrict__ eidx,
                                 int* __restrict__ degi, int* __restrict__ deg2) {
    int i = blockIdx.x * blockDim.x + threadIdx.x;
    if (i < N_EDGES) atomicAdd(degi + eidx[N_EDGES + i], 1);  // dst
    if (i < 2 * N_EDGES) atomicAdd(deg2 + eidx[i], 1);        // both endpoints
}

__global__ void k_block_sums2(const int* __restrict__ degi, const int* __restrict__ deg2,
                              int* __restrict__ partials, int n) {
    const int* deg = blockIdx.y ? deg2 : degi;
    int* part = partials + blockIdx.y * 256;
    __shared__ int sm[256];
    int i = blockIdx.x * 256 + threadIdx.x;
    sm[threadIdx.x] = (i < n) ? deg[i] : 0;
    __syncthreads();
    for (int s = 128; s > 0; s >>= 1) {
        if (threadIdx.x < s) sm[threadIdx.x] += sm[threadIdx.x + s];
        __syncthreads();
    }
    if (threadIdx.x == 0) part[blockIdx.x] = sm[0];
}

__global__ void k_scan_partials2(int* partials, int nb) {
    int* part = partials + blockIdx.x * 256;
    __shared__ int sm[256];
    int v = (threadIdx.x < nb) ? part[threadIdx.x] : 0;
    sm[threadIdx.x] = v;
    __syncthreads();
    for (int off = 1; off < 256; off <<= 1) {
        int t = (threadIdx.x >= off) ? sm[threadIdx.x - off] : 0;
        __syncthreads();
        sm[threadIdx.x] += t;
        __syncthreads();
    }
    if (threadIdx.x < nb) part[threadIdx.x] = sm[threadIdx.x] - v;
}

__global__ void k_scan_final2(const int* __restrict__ degi, const int* __restrict__ deg2,
                              const int* __restrict__ partials,
                              int* __restrict__ row_start, int* __restrict__ row2, int n) {
    const int* deg = blockIdx.y ? deg2 : degi;
    const int* part = partials + blockIdx.y * 256;
    int* row = blockIdx.y ? row2 : row_start;
    __shared__ int sm[256];
    int i = blockIdx.x * 256 + threadIdx.x;
    int v = (i < n) ? deg[i] : 0;
    sm[threadIdx.x] = v;
    __syncthreads();
    for (int off = 1; off < 256; off <<= 1) {
        int t = (threadIdx.x >= off) ? sm[threadIdx.x - off] : 0;
        __syncthreads();
        sm[threadIdx.x] += t;
        __syncthreads();
    }
    if (i < n) row[i] = part[blockIdx.x] + sm[threadIdx.x] - v;
    if (i == n - 1) row[n] = part[blockIdx.x] + sm[threadIdx.x];
}

__global__ void k_copy_cursors(const int* __restrict__ row_start, const int* __restrict__ row2,
                               int* __restrict__ cursor, int* __restrict__ cursor2) {
    int i = blockIdx.x * 256 + threadIdx.x;
    if (i < N_NODES) { cursor[i] = row_start[i]; cursor2[i] = row2[i]; }
}

__global__ void k_fill_slots_both(const int* __restrict__ eidx,
                                  int* __restrict__ cursor, int* __restrict__ cursor2,
                                  int* __restrict__ eid, int* __restrict__ eid2) {
    int i = blockIdx.x * blockDim.x + threadIdx.x;
    if (i < N_EDGES) {
        int pos = atomicAdd(cursor + eidx[N_EDGES + i], 1);
        eid[pos] = i;
    }
    if (i < 2 * N_EDGES) {
        int pos2 = atomicAdd(cursor2 + eidx[i], 1);
        eid2[pos2] = (i < N_EDGES) ? i : (i - N_EDGES);
    }
}

// ---------------- one-shot weight prep: pack everything f16, transpose nc_w1 -----------
// items: Ctp 2048 | W1e 2560 | W2e 4096 | Wm1 4096 | Wm2 4096 | ncw1t 4608  = 21504
__global__ void k_prep(const float* __restrict__ ecC /*[64][64]*/, float* __restrict__ Ctp,
                       const float* __restrict__ ew1 /*[38][128]*/, float* __restrict__ W1e,
                       const float* __restrict__ ew2 /*[128][64]*/, float* __restrict__ W2e,
                       const float* __restrict__ m1w /*[64][128]*/, float* __restrict__ Wm1,
                       const float* __restrict__ m2w /*[64][128]*/, float* __restrict__ Wm2,
                       const float* __restrict__ ncw1 /*[72][64]*/, float* __restrict__ ncw1t) {
    int i = blockIdx.x * 256 + threadIdx.x;
    if (i < 2048) {
        int j = i >> 5, k2 = i & 31;
        Ctp[i] = pk(ecC[(2 * k2) * 64 + j], ecC[(2 * k2 + 1) * 64 + j]);
        return;
    }
    i -= 2048;
    if (i < 2560) {
        int k2 = i >> 7, j = i & 127;
        float a = (2 * k2 < 38) ? ew1[(2 * k2) * 128 + j] : 0.f;
        float b = (2 * k2 + 1 < 38) ? ew1[(2 * k2 + 1) * 128 + j] : 0.f;
        W1e[i] = pk(a, b);
        return;
    }
    i -= 2560;
    if (i < 4096) {
        int k2 = i >> 6, j = i & 63;
        W2e[i] = pk(ew2[(2 * k2) * 64 + j], ew2[(2 * k2 + 1) * 64 + j]);
        return;
    }
    i -= 4096;
    if (i < 4096) {
        int k2 = i >> 7, j = i & 127;
        Wm1[i] = pk(m1w[(2 * k2) * 128 + j], m1w[(2 * k2 + 1) * 128 + j]);
        return;
    }
    i -= 4096;
    if (i < 4096) {
        int k2 = i >> 7, j = i & 127;
        Wm2[i] = pk(m2w[(2 * k2) * 128 + j], m2w[(2 * k2 + 1) * 128 + j]);
        return;
    }
    i -= 4096;
    if (i < 4608) {
        int k = i / 64, j = i - k * 64;
        ncw1t[j * 72 + k] = ncw1[k * 64 + j];
    }
}

// ---------------- edge encoder: LDS = feats/H union only; weights from L1 ---------------
// smem union (4352 floats = 17.4 KB): Fp [64][20] phase A; Hp [64][68] phase B (overlay).
__global__ __launch_bounds__(256) void k_edge_enc_tiled(
    const float* __restrict__ la, const float* __restrict__ tse,
    const int* __restrict__ bp, const int* __restrict__ tt,
    const float* __restrict__ cr, const float* __restrict__ tsp,
    const float* __restrict__ tg, const float* __restrict__ r7,
    const float* __restrict__ r30,
    const float* __restrict__ tx_emb, const float* __restrict__ bank_emb,
    const float* __restrict__ W1e /*[20 k2][128 j] packed*/, const float* __restrict__ eb1,
    const float* __restrict__ W2e /*[64 k2][64 j] packed*/, const float* __restrict__ eb2,
    float* __restrict__ eap_g /*E x 32 packed*/, int n_edges) {
    __shared__ float smem[4352];
    float* Fp = smem;             // [64][20]
    float* Hp = smem;             // [64][68] overlays after GEMM1
    int tid = threadIdx.x;
    int t0 = blockIdx.x * 64;

    {
        int el = tid & 63, g = tid >> 6;
        int e = t0 + el;
        bool ok = e < n_edges;
        float* Fr = Fp + el * 20;
        if (g == 0) {
            Fr[0] = ok ? pk(la[e], cr[e]) : 0.f;
            Fr[1] = ok ? pk(tsp[e], tg[e]) : 0.f;
            Fr[2] = ok ? pk(r7[e], r30[e]) : 0.f;
            Fr[19] = 0.f;
        } else if (g == 1) {
            float4 a = make_float4(0, 0, 0, 0), b = a;
            if (ok) { a = ((const float4*)(tse + (long)e * 8))[0];
                      b = ((const float4*)(tse + (long)e * 8))[1]; }
            Fr[3] = pk(a.x, a.y); Fr[4] = pk(a.z, a.w);
            Fr[5] = pk(b.x, b.y); Fr[6] = pk(b.z, b.w);
        } else if (g == 2) {
            float4 a = make_float4(0, 0, 0, 0), b = a;
            if (ok) { int txi = tt[e];
                      a = ((const float4*)(tx_emb + (long)txi * 8))[0];
                      b = ((const float4*)(tx_emb + (long)txi * 8))[1]; }
            Fr[7] = pk(a.x, a.y); Fr[8] = pk(a.z, a.w);
            Fr[9] = pk(b.x, b.y); Fr[10] = pk(b.z, b.w);
        } else {
            float4 a = make_float4(0, 0, 0, 0), b = a, c = a, d = a;
            if (ok) {
                int bk0 = bp[e * 2 + 0], bk1 = bp[e * 2 + 1];
                a = ((const float4*)(bank_emb + (long)bk0 * 8))[0];
                b = ((const float4*)(bank_emb + (long)bk0 * 8))[1];
                c = ((const float4*)(bank_emb + (long)bk1 * 8))[0];
                d = ((const float4*)(bank_emb + (long)bk1 * 8))[1];
            }
            Fr[11] = pk(a.x, a.y); Fr[12] = pk(a.z, a.w);
            Fr[13] = pk(b.x, b.y); Fr[14] = pk(b.z, b.w);
            Fr[15] = pk(c.x, c.y); Fr[16] = pk(c.z, c.w);
            Fr[17] = pk(d.x, d.y); Fr[18] = pk(d.z, d.w);
        }
    }
    __syncthreads();

    // GEMM1 (K2=20), W1e from L1
    int jg1 = tid & 31, eg1 = tid >> 5;
    int j1 = jg1 * 4;
    float acc1[8][4];
#pragma unroll
    for (int el = 0; el < 8; el++)
#pragma unroll
        for (int jj = 0; jj < 4; jj++) acc1[el][jj] = 0.f;
    for (int kq = 0; kq < 5; kq++) {
        float4 wv[4];
#pragma unroll
        for (int kk = 0; kk < 4; kk++)
            wv[kk] = *(const float4*)&W1e[(kq * 4 + kk) * 128 + j1];
#pragma unroll
        for (int el = 0; el < 8; el++) {
            float4 av = *(const float4*)&Fp[(eg1 * 8 + el) * 20 + kq * 4];
            const float* a = (const float*)&av;
#pragma unroll
            for (int jj = 0; jj < 4; jj++) {
                float t = acc1[el][jj];
                t = dot2f(a[0], ((const float*)&wv[0])[jj], t);
                t = dot2f(a[1], ((const float*)&wv[1])[jj], t);
                t = dot2f(a[2], ((const float*)&wv[2])[jj], t);
                t = dot2f(a[3], ((const float*)&wv[3])[jj], t);
                acc1[el][jj] = t;
            }
        }
    }
    __syncthreads();   // Fp dead; Hp overlays

    {
        float4 bv = *(const float4*)(eb1 + j1);
#pragma unroll
        for (int el = 0; el < 8; el++) {
            int row = eg1 * 8 + el;
            float x0 = fmaxf(acc1[el][0] + bv.x, 0.f);
            float x1 = fmaxf(acc1[el][1] + bv.y, 0.f);
            float x2 = fmaxf(acc1[el][2] + bv.z, 0.f);
            float x3 = fmaxf(acc1[el][3] + bv.w, 0.f);
            int c = (tid & 31) * 2;
            Hp[row * 68 + c] = pk(x0, x1);
            Hp[row * 68 + c + 1] = pk(x2, x3);
        }
    }
    __syncthreads();

    // GEMM2 (K2=64), W2e from L1 -> packed f16 ea
    {
        int jg = tid & 15, eg = tid >> 4;
        int j0 = jg * 4;
        float acc[4][4];
#pragma unroll
        for (int el = 0; el < 4; el++)
#pragma unroll
            for (int jj = 0; jj < 4; jj++) acc[el][jj] = 0.f;
        for (int kq = 0; kq < 16; kq++) {
            float4 wv[4];
#pragma unroll
            for (int kk = 0; kk < 4; kk++)
                wv[kk] = *(const float4*)&W2e[(kq * 4 + kk) * 64 + j0];
#pragma unroll
            for (int el = 0; el < 4; el++) {
                float4 av = *(const float4*)&Hp[(eg * 4 + el) * 68 + kq * 4];
                const float* a = (const float*)&av;
#pragma unroll
                for (int jj = 0; jj < 4; jj++) {
                    float t = acc[el][jj];
                    t = dot2f(a[0], ((const float*)&wv[0])[jj], t);
                    t = dot2f(a[1], ((const float*)&wv[1])[jj], t);
                    t = dot2f(a[2], ((const float*)&wv[2])[jj], t);
                    t = dot2f(a[3], ((const float*)&wv[3])[jj], t);
                    acc[el][jj] = t;
                }
            }
        }
        float4 bv = *(const float4*)(eb2 + j0);
#pragma unroll
        for (int el = 0; el < 4; el++) {
            int e = t0 + eg * 4 + el;
            if (e >= n_edges) continue;
            float2 o;
            o.x = pk(acc[el][0] + bv.x, acc[el][1] + bv.y);
            o.y = pk(acc[el][2] + bv.z, acc[el][3] + bv.w);
            *((float2*)(eap_g + (long)e * 32 + (j0 >> 1))) = o;
        }
    }
}

// ---------------- generic node-level GEMM (fp32; optional packed-f16 output) -----------
template <int K1, int K2, int JC, bool RELU, bool DIV2, bool PACKOUT>
__global__ __launch_bounds__(256) void k_node_gemm(
    const float* __restrict__ in1, int ld1,
    const float* __restrict__ in2, int ld2,
    const int* __restrict__ degi,
    const float* __restrict__ W, int ldw,
    const float* __restrict__ bias,
    float* __restrict__ out, int ldo, int nrows) {
    int n = blockIdx.x * blockDim.x + threadIdx.x;
    if (n >= nrows) return;
    int j0 = blockIdx.y * JC;
    float acc[JC];
#pragma unroll
    for (int j = 0; j < JC; j++) acc[j] = bias ? bias[j0 + j] : 0.f;
    const float* r1 = in1 + (long)n * ld1;
    for (int k = 0; k < K1; k++) {
        float v = r1[k];
        const float* wr = W + (long)k * ldw + j0;
#pragma unroll
        for (int j = 0; j < JC; j++) acc[j] = fmaf(v, wr[j], acc[j]);
    }
    if constexpr (K2 > 0) {
        float dinv = 1.f;
        if constexpr (DIV2) dinv = 1.f / ((float)degi[n] + 1e-6f);
        const float* r2 = in2 + (long)n * ld2;
        for (int k = 0; k < K2; k++) {
            float v = r2[k] * dinv;
            const float* wr = W + (long)(K1 + k) * ldw + j0;
#pragma unroll
            for (int j = 0; j < JC; j++) acc[j] = fmaf(v, wr[j], acc[j]);
        }
    }
    if constexpr (PACKOUT) {
        float* orow = out + (long)n * ldo + (j0 >> 1);
#pragma unroll
        for (int j2 = 0; j2 < JC / 2; j2++) {
            float a = acc[2 * j2], b = acc[2 * j2 + 1];
            if (RELU) { a = fmaxf(a, 0.f); b = fmaxf(b, 0.f); }
            orow[j2] = pk(a, b);
        }
    } else {
        float* orow = out + (long)n * ldo + j0;
#pragma unroll
        for (int j = 0; j < JC; j++) {
            float v = acc[j];
            if (RELU) v = fmaxf(v, 0.f);
            orow[j] = v;
        }
    }
}

// ---------------- edge-cls prep: nSp/nDp in one launch ---------------------------------
__global__ __launch_bounds__(256) void k_ec_prep(
    const float* __restrict__ ne, const float* __restrict__ ec_w1,
    float* __restrict__ nSp, float* __restrict__ nDp) {
    int n = blockIdx.x * blockDim.x + threadIdx.x;
    if (n >= N_NODES) return;
    const float* W = ec_w1 + (blockIdx.y ? 64 * 64 : 0);
    float* out = blockIdx.y ? nDp : nSp;
    float acc[64];
#pragma unroll
    for (int j = 0; j < 64; j++) acc[j] = 0.f;
    const float* r = ne + (long)n * 64;
    for (int k = 0; k < 64; k++) {
        float v = r[k];
        const float* wr = W + k * 64;
#pragma unroll
        for (int j = 0; j < 64; j++) acc[j] = fmaf(v, wr[j], acc[j]);
    }
    float* orow = out + (long)n * 32;
#pragma unroll
    for (int j2 = 0; j2 < 32; j2++) orow[j2] = pk(acc[2 * j2], acc[2 * j2 + 1]);
}

// ---------------- fused msg GEMM (f16-dot2, all-packed) + segmented sum ----------------
// smem union (4096 floats = 16.4 KB): eap [64][32] during k-loop; Mp [64][64] packed after.
__global__ __launch_bounds__(256) void k_msg_seg(
    const float* __restrict__ Pp /*N x 64 packed*/, const float* __restrict__ eap_g,
    const float* __restrict__ Wp /*[32 k2][128 j] packed, global*/,
    const float* __restrict__ bias,
    const int* __restrict__ src, const int* __restrict__ dst,
    const int* __restrict__ eid,
    float* __restrict__ s, int n_edges) {
    __shared__ float smem[4096];
    float* eap = smem;            // [64][32]
    float* Mp = smem;             // [64][64] packed, overlays
    __shared__ int sn_s[64];
    __shared__ int es_s[64];
    __shared__ int nid_s[64];
    __shared__ int bound_s[2];
    int tid = threadIdx.x;
    int t0 = blockIdx.x * 64;

    if (tid < 64) {
        int slot = t0 + tid;
        int e = (slot < n_edges) ? eid[slot] : 0;
        es_s[tid] = e;
        sn_s[tid] = src[e];
        nid_s[tid] = (slot < n_edges) ? dst[e] : -1;
    }
    if (tid == 64) bound_s[0] = (t0 > 0) ? dst[eid[t0 - 1]] : -1;
    if (tid == 65) bound_s[1] = (t0 + 64 < n_edges) ? dst[eid[t0 + 64]] : -1;
    __syncthreads();
#pragma unroll
    for (int i = 0; i < 2; i++) {
        int f = tid + 256 * i;
        int el = f >> 3, c = f & 7;
        float4 v = ((const float4*)(eap_g + (long)es_s[el] * 32))[c];
        *((float4*)&eap[el * 32 + c * 4]) = v;
    }
    __syncthreads();

    int jg = tid & 31;
    int eg = tid >> 5;
    int j0 = jg * 4;
    float acc[8][4];
#pragma unroll
    for (int el = 0; el < 8; el++)
#pragma unroll
        for (int jj = 0; jj < 4; jj++) acc[el][jj] = 0.f;

    for (int kq = 0; kq < 8; kq++) {
        float4 wv[4];
#pragma unroll
        for (int kk = 0; kk < 4; kk++) wv[kk] = *(const float4*)&Wp[(kq * 4 + kk) * 128 + j0];
#pragma unroll
        for (int el = 0; el < 8; el++) {
            float4 av = *(const float4*)&eap[(eg * 8 + el) * 32 + kq * 4];
            const float* a = (const float*)&av;
#pragma unroll
            for (int jj = 0; jj < 4; jj++) {
                float t = acc[el][jj];
                t = dot2f(a[0], ((const float*)&wv[0])[jj], t);
                t = dot2f(a[1], ((const float*)&wv[1])[jj], t);
                t = dot2f(a[2], ((const float*)&wv[2])[jj], t);
                t = dot2f(a[3], ((const float*)&wv[3])[jj], t);
                acc[el][jj] = t;
            }
        }
    }
    __syncthreads();   // eap dead; Mp overlays

    float4 bv = *(const float4*)(bias + j0);
#pragma unroll
    for (int el = 0; el < 8; el++) {
        int row = eg * 8 + el;
        float2 pv2 = *(const float2*)(Pp + (long)sn_s[row] * 64 + (j0 >> 1));
        float2 pa = upk(pv2.x), pb = upk(pv2.y);
        float2 o;
        o.x = pk(fmaxf(acc[el][0] + pa.x + bv.x, 0.f),
                 fmaxf(acc[el][1] + pa.y + bv.y, 0.f));
        o.y = pk(fmaxf(acc[el][2] + pb.x + bv.z, 0.f),
                 fmaxf(acc[el][3] + pb.y + bv.w, 0.f));
        *((float2*)&Mp[row * 64 + jg * 2]) = o;
    }
    __syncthreads();

    if (tid < 128) {
        int c = tid;
        int rows = min(64, n_edges - t0);
        int prev_n = bound_s[0], next_n = bound_s[1];
        int cur = nid_s[0];
        int seg_start = 0;
        float run = 0.f;
        bool hi = c & 1;
        int c2 = c >> 1;
        for (int r = 0; r < rows; r++) {
            int nd = nid_s[r];
            if (nd != cur) {
                if (seg_start == 0 && cur == prev_n) atomicAdd(s + (long)cur * 128 + c, run);
                else s[(long)cur * 128 + c] = run;
                cur = nd; seg_start = r; run = 0.f;
            }
            float2 u = upk(Mp[r * 64 + c2]);
            run += hi ? u.y : u.x;
        }
        if ((seg_start == 0 && cur == prev_n) || cur == next_n)
            atomicAdd(s + (long)cur * 128 + c, run);
        else s[(long)cur * 128 + c] = run;
    }
}

// ---------------- edge classifier: packed-f16 gathers, f16-dot2 math -------------------
__global__ __launch_bounds__(256) void k_edge_cls(
    const float* __restrict__ nSp, const float* __restrict__ nDp,
    const float* __restrict__ eap_g,
    const float* __restrict__ Ctp /*[64 j][32 k2] packed*/,
    const float* __restrict__ b1, const float* __restrict__ w2, const float* __restrict__ b2,
    const int* __restrict__ src, const int* __restrict__ dst,
    const int* __restrict__ uts, const int* __restrict__ tsmax,
    float* __restrict__ logits_out, float4* __restrict__ einfo) {
    int e = blockIdx.x * blockDim.x + threadIdx.x;
    if (e >= N_EDGES) return;
    int sn = src[e], dn = dst[e];
    float base[64];
    const float4* Sp4 = (const float4*)(nSp + (long)sn * 32);
    const float4* Dp4 = (const float4*)(nDp + (long)dn * 32);
#pragma unroll
    for (int i = 0; i < 8; i++) {
        float4 sv = Sp4[i];
        float4 dv = Dp4[i];
        const float* sp = (const float*)&sv;
        const float* dp = (const float*)&dv;
#pragma unroll
        for (int q = 0; q < 4; q++) {
            float2 su = upk(sp[q]), du = upk(dp[q]);
            base[8 * i + 2 * q + 0] = su.x + du.x;
            base[8 * i + 2 * q + 1] = su.y + du.y;
        }
    }
    float ap[32];
    const float4* ar = (const float4*)(eap_g + (long)e * 32);
#pragma unroll
    for (int i = 0; i < 8; i++) {
        float4 v = ar[i];
        ap[4 * i] = v.x; ap[4 * i + 1] = v.y; ap[4 * i + 2] = v.z; ap[4 * i + 3] = v.w;
    }
    float logit = b2[0];
    for (int j = 0; j < 64; j++) {
        float t = b1[j] + base[j];
        const float* wr = Ctp + j * 32;
#pragma unroll
        for (int k2 = 0; k2 < 32; k2++) t = dot2f(ap[k2], wr[k2], t);
        t = fmaxf(t, 0.f);
        logit = fmaf(t, w2[j], logit);
    }
    logits_out[e] = logit;
    float p = 1.f / (1.f + expf(-logit));
    float now = (float)(*tsmax);
    float age = fmaxf(now - (float)uts[e], 0.f);
    float decay = expf(-age / 2592000.f);
    einfo[e] = make_float4(p, decay, age, 0.f);
}

// ---------------- ts max reduction -----------------------------------------------------
__global__ void k_tsmax(const int* __restrict__ ts, int* __restrict__ out) {
    int i = blockIdx.x * blockDim.x + threadIdx.x;
    int stride = gridDim.x * blockDim.x;
    int m = 0;
    for (int t = i; t < N_EDGES; t += stride) m = max(m, ts[t]);
#pragma unroll
    for (int off = 32; off > 0; off >>= 1) m = max(m, __shfl_down(m, off));
    if ((threadIdx.x & 63) == 0) atomicMax(out, m);
}

// ---------------- per-node aggregation over incidence CSR (no atomics) -----------------
__global__ __launch_bounds__(256) void k_node_agg(
    const float4* __restrict__ einfo, const int* __restrict__ row2,
    const int* __restrict__ eid2, float* __restrict__ feat8) {
    int n = blockIdx.x * blockDim.x + threadIdx.x;
    if (n >= N_NODES) return;
    int e0 = row2[n], e1 = row2[n + 1];
    float cnt = (float)(e1 - e0);
    float sump = 0.f, maxp = 0.f, sumh = 0.f, sumpd = 0.f, sumd = 0.f;
    float sumh30 = 0.f, maxp30 = 0.f, sump30 = 0.f, suml30 = 0.f, minage = 9999.f;
    for (int idx = e0; idx < e1; idx++) {
        float4 v = einfo[eid2[idx]];
        float p = v.x, decay = v.y, age = v.z;
        float aged = age / 86400.f;
        bool high = p >= 0.7f;
        bool l30 = age <= 2592000.f;
        sump += p;
        maxp = fmaxf(maxp, p);
        sumpd += p * decay;
        sumd += decay;
        if (high) {
            sumh += 1.f;
            minage = fminf(minage, aged);
        }
        if (l30) {
            sump30 += p;
            suml30 += 1.f;
            maxp30 = fmaxf(maxp30, p);
            if (high) sumh30 += 1.f;
        }
    }
    float* f = feat8 + (long)n * 8;
    f[0] = sump / (cnt + 1e-6f);
    f[1] = maxp;
    f[2] = log1pf(sumh);
    f[3] = sumpd / (sumd + 1e-6f);
    f[4] = log1pf(sumh30);
    f[5] = maxp30;
    f[6] = sump30 / (suml30 + 1e-6f);
    f[7] = log1pf(fminf(fminf(minage, 9999.f), 90.f)) / log1pf(90.f);
}

// ---------------- node classifier ------------------------------------------------------
__global__ __launch_bounds__(256) void k_node_cls(
    const float* __restrict__ ne, const float* __restrict__ feat8,
    const float* __restrict__ w1t /*[64][72]*/, const float* __restrict__ b1,
    const float* __restrict__ gamma, const float* __restrict__ beta,
    const float* __restrict__ mean, const float* __restrict__ var,
    const float* __restrict__ w2, const float* __restrict__ b2,
    float* __restrict__ out) {
    int n = blockIdx.x * blockDim.x + threadIdx.x;
    if (n >= N_NODES) return;
    float in[72];
    const float4* nr = (const float4*)(ne + (long)n * 64);
#pragma unroll
    for (int i = 0; i < 16; i++) {
        float4 v = nr[i];
        in[4 * i] = v.x; in[4 * i + 1] = v.y; in[4 * i + 2] = v.z; in[4 * i + 3] = v.w;
    }
    const float4* fr = (const float4*)(feat8 + (long)n * 8);
    float4 f0 = fr[0], f1 = fr[1];
    in[64] = f0.x; in[65] = f0.y; in[66] = f0.z; in[67] = f0.w;
    in[68] = f1.x; in[69] = f1.y; in[70] = f1.z; in[71] = f1.w;
    float logit = b2[0];
    for (int j = 0; j < 64; j++) {
        float h = b1[j];
        const float* wr = w1t + j * 72;
#pragma unroll
        for (int k = 0; k < 72; k++) h = fmaf(in[k], wr[k], h);
        h = (h - mean[j]) * rsqrtf(var[j] + 1e-5f) * gamma[j] + beta[j];
        h = fmaxf(h, 0.f);
        logit = fmaf(h, w2[j], logit);
    }
    out[n] = logit;
}

extern "C" void kernel_launch(void* const* d_in, const int* in_sizes, int n_in,
                              void* d_out, int out_size, void* d_ws, size_t ws_size,
                              hipStream_t stream) {
    const float* x = (const float*)d_in[0];
    const int* eidx = (const int*)d_in[1];
    const int* src = eidx;
    const int* dst = eidx + N_EDGES;
    const float* la = (const float*)d_in[2];
    const float* tse = (const float*)d_in[3];
    const int* bp = (const int*)d_in[4];
    const int* tt = (const int*)d_in[5];
    const float* cr = (const float*)d_in[6];
    const float* tsp = (const float*)d_in[7];
    const float* tg = (const float*)d_in[8];
    const float* r7 = (const float*)d_in[9];
    const float* r30 = (const float*)d_in[10];
    const int* uts = (const int*)d_in[11];
    const float* tx_emb = (const float*)d_in[12];
    const float* bank_emb = (const float*)d_in[13];
    const float* ee_w1 = (const float*)d_in[14];
    const float* ee_b1 = (const float*)d_in[15];
    const float* ee_w2 = (const float*)d_in[16];
    const float* ee_b2 = (const float*)d_in[17];
    const float* msg1_w = (const float*)d_in[18];
    const float* msg1_b = (const float*)d_in[19];
    const float* upd1_w = (const float*)d_in[20];
    const float* upd1_b = (const float*)d_in[21];
    const float* msg2_w = (const float*)d_in[22];
    const float* msg2_b = (const float*)d_in[23];
    const float* upd2_w = (const float*)d_in[24];
    const float* upd2_b = (const float*)d_in[25];
    const float* ec_w1 = (const float*)d_in[26];
    const float* ec_b1 = (const float*)d_in[27];
    const float* ec_w2 = (const float*)d_in[28];
    const float* ec_b2 = (const float*)d_in[29];
    const float* nc_w1 = (const float*)d_in[30];
    const float* nc_b1 = (const float*)d_in[31];
    const float* bn_g = (const float*)d_in[32];
    const float* bn_b = (const float*)d_in[33];
    const float* bn_m = (const float*)d_in[34];
    const float* bn_v = (const float*)d_in[35];
    const float* nc_w2 = (const float*)d_in[36];
    const float* nc_b2 = (const float*)d_in[37];

    float* out_node = (float*)d_out;              // [N_NODES]
    float* out_edge = (float*)d_out + N_NODES;    // [N_EDGES]

    // workspace layout (floats)
    float* ws0 = (float*)d_ws;
    float* eap_g = ws0;                          // E*32 packed f16
    float* Pp = eap_g + (long)N_EDGES * 32;      // N*64 packed
    float* s = Pp + (long)N_NODES * 64;          // N*128 fp32
    float* h1 = s + (long)N_NODES * 128;         // N*128 fp32
    float* ne = h1 + (long)N_NODES * 128;        // N*64 fp32
    float* nSp = ne + (long)N_NODES * 64;        // N*32 packed
    float* nDp = nSp + (long)N_NODES * 32;       // N*32 packed
    float* feat8 = nDp + (long)N_NODES * 32;     // N*8
    float* Ctp = feat8 + (long)N_NODES * 8;      // 2048
    float* W1e = Ctp + 2048;                     // 2560
    float* W2e = W1e + 2560;                     // 4096
    float* Wm1 = W2e + 4096;                     // 4096
    float* Wm2 = Wm1 + 4096;                     // 4096
    float* ncw1t = Wm2 + 4096;                   // 4608
    int* tsmax = (int*)(ncw1t + 4608);           // 1
    int* degi = tsmax + 1;                       // N
    int* deg2 = degi + N_NODES;                  // N
    int* row_start = deg2 + N_NODES;             // N+1
    int* row2 = row_start + N_NODES + 1;         // N+1
    int* cursor = row2 + N_NODES + 1;            // N
    int* cursor2 = cursor + N_NODES;             // N
    int* eid = cursor2 + N_NODES;                // E
    int* eid2 = eid + N_EDGES;                   // 2E
    int* partials = eid2 + 2 * N_EDGES;          // 512
    float4* einfo = (float4*)Pp;                 // aliases Pp (dead after 2nd msg_seg)

    const int EB = (N_EDGES + 255) / 256;
    const int E2B = (2 * N_EDGES + 255) / 256;
    const int NB = (N_NODES + 255) / 256;        // 196
    const int MB = (N_EDGES + 63) / 64;          // 7813

    // ---- init ----
    hipMemsetAsync(tsmax, 0, (size_t)(1 + 2 * N_NODES) * 4, stream);  // tsmax+degi+deg2
    hipMemsetAsync(s, 0, (size_t)N_NODES * 128 * 4, stream);

    // ---- merged CSR1 + CSR2 build ----
    k_deg_count_both<<<E2B, 256, 0, stream>>>(eidx, degi, deg2);
    k_block_sums2<<<dim3(NB, 2), 256, 0, stream>>>(degi, deg2, partials, N_NODES);
    k_scan_partials2<<<2, 256, 0, stream>>>(partials, NB);
    k_scan_final2<<<dim3(NB, 2), 256, 0, stream>>>(degi, deg2, partials, row_start, row2, N_NODES);
    k_copy_cursors<<<NB, 256, 0, stream>>>(row_start, row2, cursor, cursor2);
    k_fill_slots_both<<<E2B, 256, 0, stream>>>(eidx, cursor, cursor2, eid, eid2);

    // ---- weight prep (all f16 packing + nc transpose, one launch) ----
    k_prep<<<84, 256, 0, stream>>>(ec_w1 + 128 * 64, Ctp, ee_w1, W1e, ee_w2, W2e,
                                   msg1_w + 128 * 128, Wm1, msg2_w + 128 * 128, Wm2,
                                   nc_w1, ncw1t);

    // ---- edge encoder ----
    k_edge_enc_tiled<<<MB, 256, 0, stream>>>(la, tse, bp, tt, cr, tsp, tg, r7, r30,
                                             tx_emb, bank_emb, W1e, ee_b1, W2e, ee_b2,
                                             eap_g, N_EDGES);

    // ---- SAGE layer 1 ----
    k_node_gemm<128, 0, 64, false, false, true><<<dim3(NB, 2), 256, 0, stream>>>(
        x, 128, nullptr, 0, nullptr, msg1_w, 128, nullptr, Pp, 64, N_NODES);
    k_msg_seg<<<MB, 256, 0, stream>>>(Pp, eap_g, Wm1, msg1_b, src, dst, eid, s, N_EDGES);
    k_node_gemm<128, 128, 64, true, true, false><<<dim3(NB, 2), 256, 0, stream>>>(
        x, 128, s, 128, degi, upd1_w, 128, upd1_b, h1, 128, N_NODES);

    // ---- SAGE layer 2 ----
    k_node_gemm<128, 0, 64, false, false, true><<<dim3(NB, 2), 256, 0, stream>>>(
        h1, 128, nullptr, 0, nullptr, msg2_w, 128, nullptr, Pp, 64, N_NODES);
    hipMemsetAsync(s, 0, (size_t)N_NODES * 128 * 4, stream);
    k_msg_seg<<<MB, 256, 0, stream>>>(Pp, eap_g, Wm2, msg2_b, src, dst, eid, s, N_EDGES);
    k_node_gemm<128, 128, 64, true, true, false><<<dim3(NB, 1), 256, 0, stream>>>(
        h1, 128, s, 128, degi, upd2_w, 64, upd2_b, ne, 64, N_NODES);
    // Pp dead from here -> einfo alias safe

    // ---- edge classifier prep ----
    k_ec_prep<<<dim3(NB, 2), 256, 0, stream>>>(ne, ec_w1, nSp, nDp);

    // ---- edge classifier (+ einfo pack) ----
    k_tsmax<<<256, 256, 0, stream>>>(uts, tsmax);
    k_edge_cls<<<EB, 256, 0, stream>>>(nSp, nDp, eap_g, Ctp, ec_b1, ec_w2, ec_b2,
                                       src, dst, uts, tsmax, out_edge, einfo);

    // ---- node aggregation ----
    k_node_agg<<<NB, 256, 0, stream>>>(einfo, row2, eid2, feat8);

    // ---- node classifier ----
    k_node_cls<<<NB, 256, 0, stream>>>(ne, feat8, ncw1t, nc_b1, bn_g, bn_b, bn_m, bn_v,
                                       nc_w2, nc_b2, out_node);
}